// Round 2
// baseline (7794.437 us; speedup 1.0000x reference)
//
#include <hip/hip_runtime.h>
#include <hip/hip_bf16.h>

typedef unsigned short u16;
typedef __attribute__((ext_vector_type(8))) short bf16x8;   // 8 bf16 in 4 VGPRs
typedef __attribute__((ext_vector_type(4))) float f32x4;    // MFMA acc

#define MFMA16(a, b, c) __builtin_amdgcn_mfma_f32_16x16x32_bf16((a), (b), (c), 0, 0, 0)

static constexpr int Ee = 300, EP = 320, Hh = 1024, G3 = 3072;
static constexpr int Bb = 64, Tt = 512;

// workspace layout (bytes)
static constexpr long OFF_GX   = 0L;                      // [512][3072][64] bf16 = 201326592
static constexpr long OFF_EMB  = 201326592L;              // [32768][320] bf16   = 20971520
static constexpr long OFF_WIH  = 222298112L;              // [3072][320] bf16    = 1966080
static constexpr long OFF_WHH  = 224264192L;              // [3072][1024] bf16   = 6291456
static constexpr long OFF_HBUF = 230555648L;              // 2 x [64][1024] bf16 = 262144
static constexpr long OFF_HFIN = 230817792L;              // [64][1024] f32      = 262144
static constexpr long OFF_FLAG = 231079936L;              // 64 x 16 int         = 4096

__device__ __forceinline__ u16 f2bf(float f) {
    union { float f; unsigned u; } v; v.f = f;
    unsigned u = v.u;
    return (u16)((u + 0x7fffu + ((u >> 16) & 1u)) >> 16);   // RNE
}
__device__ __forceinline__ float bf2f(u16 u) {
    union { unsigned u; float f; } v; v.u = ((unsigned)u) << 16;
    return v.f;
}
__device__ __forceinline__ float fast_sigmoid(float x) {
    return 1.f / (1.f + __expf(-x));          // x<-87 -> e^-x=inf -> 0, safe
}
__device__ __forceinline__ float fast_tanh(float x) {
    float ax = fabsf(x);
    float e = __expf(-2.f * ax);              // in (0,1], no overflow
    float t = (1.f - e) / (1.f + e);
    return copysignf(t, x);
}

// ---------------------------------------------------------------- prep ------
static constexpr long R0 = (long)Bb * Tt * EP;   // 10485760 emb gather (bf16, padded)
static constexpr long R1 = (long)G3 * EP;        // 983040   W_ih -> bf16 padded
static constexpr long R2 = (long)G3 * Hh;        // 3145728  W_hh -> bf16
static constexpr long R3 = (long)Bb * Hh;        // 65536    h0 = 0
static constexpr long R4 = 1024;                 // flags = 0

__global__ void prep_kernel(const int* __restrict__ x, const float* __restrict__ emb,
                            const float* __restrict__ wih, const float* __restrict__ whh,
                            u16* __restrict__ emb_bf, u16* __restrict__ wih_bf,
                            u16* __restrict__ whh_bf, u16* __restrict__ h0,
                            int* __restrict__ flags) {
    const long total = R0 + R1 + R2 + R3 + R4;
    for (long i = (long)blockIdx.x * blockDim.x + threadIdx.x; i < total;
         i += (long)gridDim.x * blockDim.x) {
        if (i < R0) {
            const int m = (int)(i / EP), k = (int)(i % EP);
            const int b = m & 63, t = m >> 6;
            u16 v = 0;
            if (k < Ee) {
                const int xi = x[b * Tt + t];
                v = f2bf(emb[(size_t)xi * Ee + k]);
            }
            emb_bf[i] = v;
        } else if (i < R0 + R1) {
            const long j = i - R0;
            const int k = (int)(j % EP);
            const int n = (int)(j / EP);
            wih_bf[j] = (k < Ee) ? f2bf(wih[(size_t)n * Ee + k]) : (u16)0;
        } else if (i < R0 + R1 + R2) {
            const long j = i - R0 - R1;
            whh_bf[j] = f2bf(whh[j]);
        } else if (i < R0 + R1 + R2 + R3) {
            h0[i - R0 - R1 - R2] = 0;
        } else {
            flags[i - R0 - R1 - R2 - R3] = 0;
        }
    }
}

// ------------------------------------------------------------- gx GEMM ------
// gx[t][n][b] = sum_k emb_bf[m=t*64+b][k] * wih_bf[n][k] + b_ih[n], bf16 out.
__global__ __launch_bounds__(256, 2)
void gx_gemm(const u16* __restrict__ A, const u16* __restrict__ Bm,
             const float* __restrict__ bih, u16* __restrict__ gx) {
    __shared__ __align__(16) u16 lA[128 * 32];
    __shared__ __align__(16) u16 lB[128 * 32];
    const int tid = threadIdx.x;
    const int lane = tid & 63;
    const int wv = tid >> 6;
    const int quad = lane >> 4, l15 = lane & 15;
    const int m0 = blockIdx.x * 128;
    const int n0 = blockIdx.y * 128;
    const int mo = (wv & 1) * 64, no = (wv >> 1) * 64;
    const int srow = tid >> 2;          // 0..63
    const int sseg = tid & 3;

    f32x4 acc[4][4] = {};

    for (int s = 0; s < 10; ++s) {
        const int k0 = s * 32;
        __syncthreads();
#pragma unroll
        for (int p = 0; p < 2; ++p) {
            const u16* ga = A + (size_t)(m0 + p * 64 + srow) * EP + k0 + sseg * 8;
            u16* la = &lA[p * 2048 + wv * 512];     // wave-uniform base; HW adds lane*16B
            __builtin_amdgcn_global_load_lds(
                (const __attribute__((address_space(1))) void*)ga,
                (__attribute__((address_space(3))) void*)la, 16, 0, 0);
            const u16* gb = Bm + (size_t)(n0 + p * 64 + srow) * EP + k0 + sseg * 8;
            u16* lb = &lB[p * 2048 + wv * 512];
            __builtin_amdgcn_global_load_lds(
                (const __attribute__((address_space(1))) void*)gb,
                (__attribute__((address_space(3))) void*)lb, 16, 0, 0);
        }
        __syncthreads();   // compiler emits vmcnt(0) before s_barrier -> LDS ready

        bf16x8 af[4], bfr[4];
#pragma unroll
        for (int mt = 0; mt < 4; ++mt)
            af[mt] = *(const bf16x8*)&lA[(mo + mt * 16 + l15) * 32 + quad * 8];
#pragma unroll
        for (int nt = 0; nt < 4; ++nt)
            bfr[nt] = *(const bf16x8*)&lB[(no + nt * 16 + l15) * 32 + quad * 8];
#pragma unroll
        for (int mt = 0; mt < 4; ++mt)
#pragma unroll
            for (int nt = 0; nt < 4; ++nt)
                acc[mt][nt] = MFMA16(af[mt], bfr[nt], acc[mt][nt]);
    }

    // C layout: row m = quad*4+r, col n = lane&15
#pragma unroll
    for (int mt = 0; mt < 4; ++mt) {
        const int mg = m0 + mo + mt * 16 + quad * 4;
        const int t = mg >> 6, b0 = mg & 63;
#pragma unroll
        for (int nt = 0; nt < 4; ++nt) {
            const int n = n0 + no + nt * 16 + l15;
            const float bi = bih[n];
            ushort4 vv;
            vv.x = f2bf(acc[mt][nt][0] + bi);
            vv.y = f2bf(acc[mt][nt][1] + bi);
            vv.z = f2bf(acc[mt][nt][2] + bi);
            vv.w = f2bf(acc[mt][nt][3] + bi);
            *(ushort4*)&gx[((size_t)t * G3 + n) * 64 + b0] = vv;
        }
    }
}

// ---------------------------------------------------------------- scan ------
// 64 wgs x 256 thr, REGULAR launch (64 blocks < 256 CUs -> all resident, no
// dispatch deadlock). wg owns 16 h-cols; its 3 gate W-slices live in registers
// as MFMA B-fragments. One-sided flag barrier per step; h double-buffered bf16.
__global__ __launch_bounds__(256, 1)
void scan_kernel(const u16* __restrict__ whh, const float* __restrict__ bhh,
                 const u16* __restrict__ gx, u16* __restrict__ hbuf,
                 float* __restrict__ hfin, const float* __restrict__ wfc,
                 const float* __restrict__ bfc, float* __restrict__ out,
                 int* __restrict__ flags) {
    const int wg = blockIdx.x;            // 0..63
    const int w = threadIdx.x >> 6;       // wave -> b-row block
    const int lane = threadIdx.x & 63;
    const int quad = lane >> 4, l15 = lane & 15;
    const int c0 = wg * 16;

    // persistent W fragments: B-frag for col c0+l15 of gate g, k = s*32+quad*8+..
    bf16x8 wf[3][32];
#pragma unroll
    for (int g = 0; g < 3; ++g) {
        const size_t rbase = (size_t)(g * 1024 + c0 + l15) * 1024;
#pragma unroll
        for (int s = 0; s < 32; ++s)
            wf[g][s] = *(const bf16x8*)&whh[rbase + s * 32 + quad * 8];
    }
    const float bh0 = bhh[c0 + l15];
    const float bh1 = bhh[1024 + c0 + l15];
    const float bh2 = bhh[2048 + c0 + l15];

    f32x4 hO = {0.f, 0.f, 0.f, 0.f};      // fp32 master h (b=16w+quad*4+r, j=c0+l15)

    const int arow = (w * 16 + l15) * 1024 + quad * 8;         // A-frag base
    const int hwrow = (w * 16 + quad * 4) * 1024 + c0 + l15;   // h write base (+r*1024)
    const int gxb = w * 16 + quad * 4;

    for (int t = 0; t < 512; ++t) {
        const u16* hc = hbuf + (t & 1) * 65536;
        u16* hn = hbuf + ((t + 1) & 1) * 65536;

        // this step's precomputed input projections (no cross-wg dependency)
        const size_t gbase = (size_t)t * G3 + c0 + l15;
        ushort4 gv0 = *(const ushort4*)&gx[(gbase) * 64 + gxb];
        ushort4 gv1 = *(const ushort4*)&gx[(gbase + 1024) * 64 + gxb];
        ushort4 gv2 = *(const ushort4*)&gx[(gbase + 2048) * 64 + gxb];

        f32x4 a0 = {}, a1 = {}, a2 = {};
        // K-loop: depth-12 software-pipelined A-frag prefetch from global h
        bf16x8 af[12];
#pragma unroll
        for (int s = 0; s < 12; ++s) af[s] = *(const bf16x8*)&hc[arow + s * 32];
#pragma unroll
        for (int s = 0; s < 32; ++s) {
            const bf16x8 cur = af[s % 12];
            if (s < 20) af[s % 12] = *(const bf16x8*)&hc[arow + (s + 12) * 32];
            a0 = MFMA16(cur, wf[0][s], a0);
            a1 = MFMA16(cur, wf[1][s], a1);
            a2 = MFMA16(cur, wf[2][s], a2);
        }

#pragma unroll
        for (int r = 0; r < 4; ++r) {
            const float xr = bf2f(((const u16*)&gv0)[r]);
            const float xz = bf2f(((const u16*)&gv1)[r]);
            const float xn = bf2f(((const u16*)&gv2)[r]);
            const float rg = fast_sigmoid(xr + a0[r] + bh0);
            const float zg = fast_sigmoid(xz + a1[r] + bh1);
            const float ng = fast_tanh(xn + rg * (a2[r] + bh2));
            const float hv = (1.f - zg) * ng + zg * hO[r];
            hO[r] = hv;
            hn[hwrow + r * 1024] = f2bf(hv);
            if (t == 511) hfin[hwrow + r * 1024] = hv;
        }

        // ---- one-sided flag barrier ----
        __builtin_amdgcn_fence(__ATOMIC_RELEASE, "agent");   // h writes visible
        __syncthreads();                                      // all waves fenced
        if (threadIdx.x == 0)
            __hip_atomic_store(&flags[wg * 16], t + 1, __ATOMIC_RELAXED,
                               __HIP_MEMORY_SCOPE_AGENT);
        if (w == 0) {
            while (__hip_atomic_load(&flags[lane * 16], __ATOMIC_RELAXED,
                                     __HIP_MEMORY_SCOPE_AGENT) < t + 1) {}
        }
        __syncthreads();
        __builtin_amdgcn_fence(__ATOMIC_ACQUIRE, "agent");   // invalidate caches
    }

    // fused FC head: wg -> batch row b = wg; wave w -> outputs w, w+4
    const int b = wg;
    for (int p = w; p < 5; p += 4) {
        float sum = 0.f;
        for (int k = lane; k < 1024; k += 64)
            sum += hfin[b * 1024 + k] * wfc[p * 1024 + k];
#pragma unroll
        for (int off = 32; off > 0; off >>= 1)
            sum += __shfl_down(sum, off);
        if (lane == 0) out[b * 5 + p] = sum + bfc[p];
    }
}

// --------------------------------------------------------------- launch -----
extern "C" void kernel_launch(void* const* d_in, const int* in_sizes, int n_in,
                              void* d_out, int out_size, void* d_ws, size_t ws_size,
                              hipStream_t stream) {
    const int*   x   = (const int*)d_in[0];
    const float* emb = (const float*)d_in[1];
    const float* wih = (const float*)d_in[2];
    const float* whh = (const float*)d_in[3];
    const float* bih = (const float*)d_in[4];
    const float* bhh = (const float*)d_in[5];
    const float* wfc = (const float*)d_in[6];
    const float* bfc = (const float*)d_in[7];
    float* out = (float*)d_out;

    char* ws = (char*)d_ws;
    u16*   gxw   = (u16*)(ws + OFF_GX);
    u16*   embbf = (u16*)(ws + OFF_EMB);
    u16*   wihbf = (u16*)(ws + OFF_WIH);
    u16*   whhbf = (u16*)(ws + OFF_WHH);
    u16*   hbuf  = (u16*)(ws + OFF_HBUF);
    float* hfin  = (float*)(ws + OFF_HFIN);
    int*   flags = (int*)(ws + OFF_FLAG);

    prep_kernel<<<8192, 256, 0, stream>>>(x, emb, wih, whh, embbf, wihbf, whhbf,
                                          hbuf, flags);

    gx_gemm<<<dim3(256, 24), 256, 0, stream>>>(embbf, wihbf, bih, gxw);

    scan_kernel<<<64, 256, 0, stream>>>(whhbf, bhh, gxw, hbuf, hfin, wfc, bfc,
                                        out, flags);
}

// Round 3
// 5772.309 us; speedup vs baseline: 1.3503x; 1.3503x over previous
//
#include <hip/hip_runtime.h>
#include <hip/hip_bf16.h>

typedef unsigned short u16;
typedef unsigned long long u64;
typedef __attribute__((ext_vector_type(8))) short bf16x8;   // 8 bf16 in 4 VGPRs
typedef __attribute__((ext_vector_type(4))) float f32x4;    // MFMA acc

#define MFMA16(a, b, c) __builtin_amdgcn_mfma_f32_16x16x32_bf16((a), (b), (c), 0, 0, 0)

static constexpr int Ee = 300, EP = 320, Hh = 1024, G3 = 3072;
static constexpr int Bb = 64, Tt = 512;

// workspace layout (bytes)
static constexpr long OFF_GX   = 0L;                      // [512][3072][64] bf16 = 201326592
static constexpr long OFF_EMB  = 201326592L;              // [32768][320] bf16   = 20971520
static constexpr long OFF_WIH  = 222298112L;              // [3072][320] bf16    = 1966080
static constexpr long OFF_WHH  = 224264192L;              // [3072][1024] bf16   = 6291456
static constexpr long OFF_HBUF = 230555648L;              // 2 x [64][1024] bf16 = 262144
static constexpr long OFF_FLAG = 230817792L;              // 64 x 16 int         = 4096

__device__ __forceinline__ u16 f2bf(float f) {
    union { float f; unsigned u; } v; v.f = f;
    unsigned u = v.u;
    return (u16)((u + 0x7fffu + ((u >> 16) & 1u)) >> 16);   // RNE
}
__device__ __forceinline__ float bf2f(u16 u) {
    union { unsigned u; float f; } v; v.u = ((unsigned)u) << 16;
    return v.f;
}
__device__ __forceinline__ float fast_sigmoid(float x) {
    return 1.f / (1.f + __expf(-x));
}
__device__ __forceinline__ float fast_tanh(float x) {
    float ax = fabsf(x);
    float e = __expf(-2.f * ax);
    float t = (1.f - e) / (1.f + e);
    return copysignf(t, x);
}

// ---------------------------------------------------------------- prep ------
static constexpr long R0 = (long)Bb * Tt * EP;   // emb gather (bf16, padded)
static constexpr long R1 = (long)G3 * EP;        // W_ih -> bf16 padded
static constexpr long R2 = (long)G3 * Hh;        // W_hh -> bf16
static constexpr long R3 = (long)Bb * Hh;        // h0 = 0
static constexpr long R4 = 1024;                 // flags = 0
static constexpr long R5 = 320;                  // out = bias (d_out is poisoned!)

__global__ void prep_kernel(const int* __restrict__ x, const float* __restrict__ emb,
                            const float* __restrict__ wih, const float* __restrict__ whh,
                            const float* __restrict__ bfc,
                            u16* __restrict__ emb_bf, u16* __restrict__ wih_bf,
                            u16* __restrict__ whh_bf, u16* __restrict__ h0,
                            int* __restrict__ flags, float* __restrict__ out) {
    const long total = R0 + R1 + R2 + R3 + R4 + R5;
    for (long i = (long)blockIdx.x * blockDim.x + threadIdx.x; i < total;
         i += (long)gridDim.x * blockDim.x) {
        if (i < R0) {
            const int m = (int)(i / EP), k = (int)(i % EP);
            const int b = m & 63, t = m >> 6;
            u16 v = 0;
            if (k < Ee) {
                const int xi = x[b * Tt + t];
                v = f2bf(emb[(size_t)xi * Ee + k]);
            }
            emb_bf[i] = v;
        } else if (i < R0 + R1) {
            const long j = i - R0;
            const int k = (int)(j % EP);
            const int n = (int)(j / EP);
            wih_bf[j] = (k < Ee) ? f2bf(wih[(size_t)n * Ee + k]) : (u16)0;
        } else if (i < R0 + R1 + R2) {
            const long j = i - R0 - R1;
            whh_bf[j] = f2bf(whh[j]);
        } else if (i < R0 + R1 + R2 + R3) {
            h0[i - R0 - R1 - R2] = 0;
        } else if (i < R0 + R1 + R2 + R3 + R4) {
            flags[i - R0 - R1 - R2 - R3] = 0;
        } else {
            const long j = i - R0 - R1 - R2 - R3 - R4;
            out[j] = bfc[j % 5];
        }
    }
}

// ------------------------------------------------------------- gx GEMM ------
// gx[t][n][b] = sum_k emb_bf[m=t*64+b][k] * wih_bf[n][k] + b_ih[n], bf16 out.
__global__ __launch_bounds__(256, 2)
void gx_gemm(const u16* __restrict__ A, const u16* __restrict__ Bm,
             const float* __restrict__ bih, u16* __restrict__ gx) {
    __shared__ __align__(16) u16 lA[128 * 32];
    __shared__ __align__(16) u16 lB[128 * 32];
    const int tid = threadIdx.x;
    const int lane = tid & 63;
    const int wv = tid >> 6;
    const int quad = lane >> 4, l15 = lane & 15;
    const int m0 = blockIdx.x * 128;
    const int n0 = blockIdx.y * 128;
    const int mo = (wv & 1) * 64, no = (wv >> 1) * 64;
    const int srow = tid >> 2;
    const int sseg = tid & 3;

    f32x4 acc[4][4] = {};

    for (int s = 0; s < 10; ++s) {
        const int k0 = s * 32;
        __syncthreads();
#pragma unroll
        for (int p = 0; p < 2; ++p) {
            const u16* ga = A + (size_t)(m0 + p * 64 + srow) * EP + k0 + sseg * 8;
            u16* la = &lA[p * 2048 + wv * 512];
            __builtin_amdgcn_global_load_lds(
                (const __attribute__((address_space(1))) void*)ga,
                (__attribute__((address_space(3))) void*)la, 16, 0, 0);
            const u16* gb = Bm + (size_t)(n0 + p * 64 + srow) * EP + k0 + sseg * 8;
            u16* lb = &lB[p * 2048 + wv * 512];
            __builtin_amdgcn_global_load_lds(
                (const __attribute__((address_space(1))) void*)gb,
                (__attribute__((address_space(3))) void*)lb, 16, 0, 0);
        }
        __syncthreads();

        bf16x8 af[4], bfr[4];
#pragma unroll
        for (int mt = 0; mt < 4; ++mt)
            af[mt] = *(const bf16x8*)&lA[(mo + mt * 16 + l15) * 32 + quad * 8];
#pragma unroll
        for (int nt = 0; nt < 4; ++nt)
            bfr[nt] = *(const bf16x8*)&lB[(no + nt * 16 + l15) * 32 + quad * 8];
#pragma unroll
        for (int mt = 0; mt < 4; ++mt)
#pragma unroll
            for (int nt = 0; nt < 4; ++nt)
                acc[mt][nt] = MFMA16(af[mt], bfr[nt], acc[mt][nt]);
    }

    // C layout: row m = quad*4+r, col n = lane&15
#pragma unroll
    for (int mt = 0; mt < 4; ++mt) {
        const int mg = m0 + mo + mt * 16 + quad * 4;
        const int t = mg >> 6, b0 = mg & 63;
#pragma unroll
        for (int nt = 0; nt < 4; ++nt) {
            const int n = n0 + no + nt * 16 + l15;
            const float bi = bih[n];
            ushort4 vv;
            vv.x = f2bf(acc[mt][nt][0] + bi);
            vv.y = f2bf(acc[mt][nt][1] + bi);
            vv.z = f2bf(acc[mt][nt][2] + bi);
            vv.w = f2bf(acc[mt][nt][3] + bi);
            *(ushort4*)&gx[((size_t)t * G3 + n) * 64 + b0] = vv;
        }
    }
}

// ---------------------------------------------------------------- scan ------
// 64 wgs x 256 thr. NO fences anywhere: read-only data (W_hh, gx, W_fc) stays
// warm in L1/L2 across all 512 steps. Shared mutable state (h, flags) goes
// through agent-scope relaxed atomics only -> coherent point (MALL), exactly
// like cross-XCD atomicAdd. Barrier: h stores -> __syncthreads (drains vmcnt,
// stores acked at coherent point) -> flag store -> 64-flag spin -> syncthreads.
__global__ __launch_bounds__(256, 1)
void scan_kernel(const u16* __restrict__ whh, const float* __restrict__ bhh,
                 const u16* __restrict__ gx, u16* __restrict__ hbuf,
                 const float* __restrict__ wfc, float* __restrict__ out,
                 int* __restrict__ flags) {
    const int wg = blockIdx.x;            // 0..63
    const int w = threadIdx.x >> 6;       // wave -> b-row block
    const int lane = threadIdx.x & 63;
    const int quad = lane >> 4, l15 = lane & 15;
    const int c0 = wg * 16;

    // persistent W fragments: B-frag for col c0+l15 of gate g, k = s*32+quad*8+..
    bf16x8 wf[3][32];
#pragma unroll
    for (int g = 0; g < 3; ++g) {
        const size_t rbase = (size_t)(g * 1024 + c0 + l15) * 1024;
#pragma unroll
        for (int s = 0; s < 32; ++s)
            wf[g][s] = *(const bf16x8*)&whh[rbase + s * 32 + quad * 8];
    }
    const float bh0 = bhh[c0 + l15];
    const float bh1 = bhh[1024 + c0 + l15];
    const float bh2 = bhh[2048 + c0 + l15];

    f32x4 hO = {0.f, 0.f, 0.f, 0.f};      // fp32 master h (b=16w+quad*4+r, j=c0+l15)

    const int arow = (w * 16 + l15) * 1024 + quad * 8;         // A-frag base
    const int hwrow = (w * 16 + quad * 4) * 1024 + c0 + l15;   // h write base (+r*1024)
    const int gxb = w * 16 + quad * 4;

    union HF { u64 q[2]; bf16x8 v; };

    for (int t = 0; t < 512; ++t) {
        const u16* hc = hbuf + (t & 1) * 65536;
        u16* hn = hbuf + ((t + 1) & 1) * 65536;

        // this step's precomputed input projections (read-only, normal loads)
        const size_t gbase = (size_t)t * G3 + c0 + l15;
        ushort4 gv0 = *(const ushort4*)&gx[(gbase) * 64 + gxb];
        ushort4 gv1 = *(const ushort4*)&gx[(gbase + 1024) * 64 + gxb];
        ushort4 gv2 = *(const ushort4*)&gx[(gbase + 2048) * 64 + gxb];

        f32x4 a0 = {}, a1 = {}, a2 = {};
        // K-loop: depth-12 pipelined A-frag prefetch; agent-scope loads bypass
        // stale L1/L2 and read the coherent point.
        HF af[12];
#pragma unroll
        for (int s = 0; s < 12; ++s) {
            const u16* p = &hc[arow + s * 32];
            af[s].q[0] = __hip_atomic_load((const u64*)p, __ATOMIC_RELAXED,
                                           __HIP_MEMORY_SCOPE_AGENT);
            af[s].q[1] = __hip_atomic_load((const u64*)(p + 4), __ATOMIC_RELAXED,
                                           __HIP_MEMORY_SCOPE_AGENT);
        }
#pragma unroll
        for (int s = 0; s < 32; ++s) {
            const bf16x8 cur = af[s % 12].v;
            if (s < 20) {
                const u16* p = &hc[arow + (s + 12) * 32];
                af[s % 12].q[0] = __hip_atomic_load((const u64*)p, __ATOMIC_RELAXED,
                                                    __HIP_MEMORY_SCOPE_AGENT);
                af[s % 12].q[1] = __hip_atomic_load((const u64*)(p + 4), __ATOMIC_RELAXED,
                                                    __HIP_MEMORY_SCOPE_AGENT);
            }
            a0 = MFMA16(cur, wf[0][s], a0);
            a1 = MFMA16(cur, wf[1][s], a1);
            a2 = MFMA16(cur, wf[2][s], a2);
        }

#pragma unroll
        for (int r = 0; r < 4; ++r) {
            const float xr = bf2f(((const u16*)&gv0)[r]);
            const float xz = bf2f(((const u16*)&gv1)[r]);
            const float xn = bf2f(((const u16*)&gv2)[r]);
            const float rg = fast_sigmoid(xr + a0[r] + bh0);
            const float zg = fast_sigmoid(xz + a1[r] + bh1);
            const float ng = fast_tanh(xn + rg * (a2[r] + bh2));
            const float hv = (1.f - zg) * ng + zg * hO[r];
            hO[r] = hv;
            // agent-scope store: write-through to coherent point
            __hip_atomic_store(&hn[hwrow + r * 1024], f2bf(hv), __ATOMIC_RELAXED,
                               __HIP_MEMORY_SCOPE_AGENT);
        }

        // ---- flag barrier (no fences) ----
        __syncthreads();   // s_waitcnt vmcnt(0) before s_barrier: h stores acked
        if (threadIdx.x == 0)
            __hip_atomic_store(&flags[wg * 16], t + 1, __ATOMIC_RELAXED,
                               __HIP_MEMORY_SCOPE_AGENT);
        if (w == 0) {
            while (__hip_atomic_load(&flags[lane * 16], __ATOMIC_RELAXED,
                                     __HIP_MEMORY_SCOPE_AGENT) < t + 1) {}
        }
        __syncthreads();
    }

    // fused FC head from registers: hO[r] holds h_final(b=16w+quad*4+r, j=c0+l15).
    // Reduce over the 16 l15 lanes, one device-scope atomicAdd per (b,p).
    for (int p = 0; p < 5; ++p) {
        const float wv = wfc[p * 1024 + c0 + l15];
#pragma unroll
        for (int r = 0; r < 4; ++r) {
            float v = hO[r] * wv;
            v += __shfl_xor(v, 1);
            v += __shfl_xor(v, 2);
            v += __shfl_xor(v, 4);
            v += __shfl_xor(v, 8);
            if (l15 == 0)
                atomicAdd(&out[(w * 16 + quad * 4 + r) * 5 + p], v);
        }
    }
}

// --------------------------------------------------------------- launch -----
extern "C" void kernel_launch(void* const* d_in, const int* in_sizes, int n_in,
                              void* d_out, int out_size, void* d_ws, size_t ws_size,
                              hipStream_t stream) {
    const int*   x   = (const int*)d_in[0];
    const float* emb = (const float*)d_in[1];
    const float* wih = (const float*)d_in[2];
    const float* whh = (const float*)d_in[3];
    const float* bih = (const float*)d_in[4];
    const float* bhh = (const float*)d_in[5];
    const float* wfc = (const float*)d_in[6];
    const float* bfc = (const float*)d_in[7];
    float* out = (float*)d_out;

    char* ws = (char*)d_ws;
    u16*   gxw   = (u16*)(ws + OFF_GX);
    u16*   embbf = (u16*)(ws + OFF_EMB);
    u16*   wihbf = (u16*)(ws + OFF_WIH);
    u16*   whhbf = (u16*)(ws + OFF_WHH);
    u16*   hbuf  = (u16*)(ws + OFF_HBUF);
    int*   flags = (int*)(ws + OFF_FLAG);

    prep_kernel<<<8192, 256, 0, stream>>>(x, emb, wih, whh, bfc, embbf, wihbf,
                                          whhbf, hbuf, flags, out);

    gx_gemm<<<dim3(256, 24), 256, 0, stream>>>(embbf, wihbf, bih, gxw);

    scan_kernel<<<64, 256, 0, stream>>>(whhbf, bhh, gxw, hbuf, wfc, out, flags);
}

// Round 4
// 5089.136 us; speedup vs baseline: 1.5316x; 1.1342x over previous
//
#include <hip/hip_runtime.h>
#include <hip/hip_bf16.h>

typedef unsigned short u16;
typedef unsigned long long u64;
typedef __attribute__((ext_vector_type(8))) short bf16x8;   // 8 bf16 in 4 VGPRs
typedef __attribute__((ext_vector_type(4))) float f32x4;    // MFMA acc

#define MFMA16(a, b, c) __builtin_amdgcn_mfma_f32_16x16x32_bf16((a), (b), (c), 0, 0, 0)

static constexpr int Ee = 300, EP = 320, Hh = 1024, G3 = 3072;
static constexpr int Bb = 64, Tt = 512;

// workspace layout (bytes)
static constexpr long OFF_GX   = 0L;                      // [512][3072][64] bf16 = 201326592
static constexpr long OFF_EMB  = 201326592L;              // [32768][320] bf16   = 20971520
static constexpr long OFF_WIH  = 222298112L;              // [3072][320] bf16    = 1966080
static constexpr long OFF_WHH  = 224264192L;              // [3072][1024] bf16   = 6291456
static constexpr long OFF_HBUF = 230555648L;              // 2 x [64][1024] bf16 = 262144
static constexpr long OFF_FLAG = 230817792L;              // 64 x 16 int         = 4096

__device__ __forceinline__ u16 f2bf(float f) {
    union { float f; unsigned u; } v; v.f = f;
    unsigned u = v.u;
    return (u16)((u + 0x7fffu + ((u >> 16) & 1u)) >> 16);   // RNE
}
__device__ __forceinline__ float bf2f(u16 u) {
    union { unsigned u; float f; } v; v.u = ((unsigned)u) << 16;
    return v.f;
}
__device__ __forceinline__ float fast_sigmoid(float x) {
    return 1.f / (1.f + __expf(-x));
}
__device__ __forceinline__ float fast_tanh(float x) {
    float ax = fabsf(x);
    float e = __expf(-2.f * ax);
    float t = (1.f - e) / (1.f + e);
    return copysignf(t, x);
}

// ---------------------------------------------------------------- prep ------
static constexpr long R0 = (long)Bb * Tt * EP;   // emb gather (bf16, padded)
static constexpr long R1 = (long)G3 * EP;        // W_ih -> bf16 padded
static constexpr long R2 = (long)G3 * Hh;        // W_hh -> bf16
static constexpr long R3 = (long)Bb * Hh;        // h0 = 0
static constexpr long R4 = 1024;                 // flags = 0
static constexpr long R5 = 320;                  // out = bias (d_out is poisoned!)

__global__ void prep_kernel(const int* __restrict__ x, const float* __restrict__ emb,
                            const float* __restrict__ wih, const float* __restrict__ whh,
                            const float* __restrict__ bfc,
                            u16* __restrict__ emb_bf, u16* __restrict__ wih_bf,
                            u16* __restrict__ whh_bf, u16* __restrict__ h0,
                            int* __restrict__ flags, float* __restrict__ out) {
    const long total = R0 + R1 + R2 + R3 + R4 + R5;
    for (long i = (long)blockIdx.x * blockDim.x + threadIdx.x; i < total;
         i += (long)gridDim.x * blockDim.x) {
        if (i < R0) {
            const int m = (int)(i / EP), k = (int)(i % EP);
            const int b = m & 63, t = m >> 6;
            u16 v = 0;
            if (k < Ee) {
                const int xi = x[b * Tt + t];
                v = f2bf(emb[(size_t)xi * Ee + k]);
            }
            emb_bf[i] = v;
        } else if (i < R0 + R1) {
            const long j = i - R0;
            const int k = (int)(j % EP);
            const int n = (int)(j / EP);
            wih_bf[j] = (k < Ee) ? f2bf(wih[(size_t)n * Ee + k]) : (u16)0;
        } else if (i < R0 + R1 + R2) {
            const long j = i - R0 - R1;
            whh_bf[j] = f2bf(whh[j]);
        } else if (i < R0 + R1 + R2 + R3) {
            h0[i - R0 - R1 - R2] = 0;
        } else if (i < R0 + R1 + R2 + R3 + R4) {
            flags[i - R0 - R1 - R2 - R3] = 0;
        } else {
            const long j = i - R0 - R1 - R2 - R3 - R4;
            out[j] = bfc[j % 5];
        }
    }
}

// ------------------------------------------------------------- gx GEMM ------
// gx[t][n][b] = sum_k emb_bf[m=t*64+b][k] * wih_bf[n][k] + b_ih[n], bf16 out.
__global__ __launch_bounds__(256, 2)
void gx_gemm(const u16* __restrict__ A, const u16* __restrict__ Bm,
             const float* __restrict__ bih, u16* __restrict__ gx) {
    __shared__ __align__(16) u16 lA[128 * 32];
    __shared__ __align__(16) u16 lB[128 * 32];
    const int tid = threadIdx.x;
    const int lane = tid & 63;
    const int wv = tid >> 6;
    const int quad = lane >> 4, l15 = lane & 15;
    const int m0 = blockIdx.x * 128;
    const int n0 = blockIdx.y * 128;
    const int mo = (wv & 1) * 64, no = (wv >> 1) * 64;
    const int srow = tid >> 2;
    const int sseg = tid & 3;

    f32x4 acc[4][4] = {};

    for (int s = 0; s < 10; ++s) {
        const int k0 = s * 32;
        __syncthreads();
#pragma unroll
        for (int p = 0; p < 2; ++p) {
            const u16* ga = A + (size_t)(m0 + p * 64 + srow) * EP + k0 + sseg * 8;
            u16* la = &lA[p * 2048 + wv * 512];
            __builtin_amdgcn_global_load_lds(
                (const __attribute__((address_space(1))) void*)ga,
                (__attribute__((address_space(3))) void*)la, 16, 0, 0);
            const u16* gb = Bm + (size_t)(n0 + p * 64 + srow) * EP + k0 + sseg * 8;
            u16* lb = &lB[p * 2048 + wv * 512];
            __builtin_amdgcn_global_load_lds(
                (const __attribute__((address_space(1))) void*)gb,
                (__attribute__((address_space(3))) void*)lb, 16, 0, 0);
        }
        __syncthreads();

        bf16x8 af[4], bfr[4];
#pragma unroll
        for (int mt = 0; mt < 4; ++mt)
            af[mt] = *(const bf16x8*)&lA[(mo + mt * 16 + l15) * 32 + quad * 8];
#pragma unroll
        for (int nt = 0; nt < 4; ++nt)
            bfr[nt] = *(const bf16x8*)&lB[(no + nt * 16 + l15) * 32 + quad * 8];
#pragma unroll
        for (int mt = 0; mt < 4; ++mt)
#pragma unroll
            for (int nt = 0; nt < 4; ++nt)
                acc[mt][nt] = MFMA16(af[mt], bfr[nt], acc[mt][nt]);
    }

    // C layout: row m = quad*4+r, col n = lane&15
#pragma unroll
    for (int mt = 0; mt < 4; ++mt) {
        const int mg = m0 + mo + mt * 16 + quad * 4;
        const int t = mg >> 6, b0 = mg & 63;
#pragma unroll
        for (int nt = 0; nt < 4; ++nt) {
            const int n = n0 + no + nt * 16 + l15;
            const float bi = bih[n];
            ushort4 vv;
            vv.x = f2bf(acc[mt][nt][0] + bi);
            vv.y = f2bf(acc[mt][nt][1] + bi);
            vv.z = f2bf(acc[mt][nt][2] + bi);
            vv.w = f2bf(acc[mt][nt][3] + bi);
            *(ushort4*)&gx[((size_t)t * G3 + n) * 64 + b0] = vv;
        }
    }
}

// ---------------------------------------------------------------- scan ------
// 64 wgs x 256 thr. K-SPLIT across waves: wave w owns K-slice [256w,256w+256)
// -> only 24 W-fragments (96 VGPR) per wave, guaranteed register-resident (no
// per-step rematerialization, the R3 stall). Each wave MFMAs all 4 M-tiles
// over its K-quarter; partials reduced across waves through LDS. Exchange of
// h and flags via agent-scope relaxed atomics (MALL), no fences -> read-only
// data stays warm in L1/L2.
__global__ __launch_bounds__(256, 1)
void scan_kernel(const u16* __restrict__ whh, const float* __restrict__ bhh,
                 const u16* __restrict__ gx, u16* __restrict__ hbuf,
                 const float* __restrict__ wfc, float* __restrict__ out,
                 int* __restrict__ flags) {
    __shared__ __align__(16) float red[12][4][256];   // [g*4+mt][wave][elem] 48 KB
    const int wg = blockIdx.x;            // 0..63 -> h-cols 16wg..16wg+16
    const int w = threadIdx.x >> 6;       // wave -> K-quarter AND gate-math M-tile
    const int lane = threadIdx.x & 63;
    const int quad = lane >> 4, l15 = lane & 15;
    const int c0 = wg * 16;
    const int ks0 = w * 8;                // first 32-wide k-chunk of this wave

    // register-resident W: B-frag for col c0+l15, gate g, chunk ks0+s
    bf16x8 wfr[3][8];
#pragma unroll
    for (int g = 0; g < 3; ++g) {
        const size_t rbase = (size_t)(g * 1024 + c0 + l15) * 1024;
#pragma unroll
        for (int s = 0; s < 8; ++s)
            wfr[g][s] = *(const bf16x8*)&whh[rbase + (ks0 + s) * 32 + quad * 8];
    }
    const float bh0 = bhh[c0 + l15];
    const float bh1 = bhh[1024 + c0 + l15];
    const float bh2 = bhh[2048 + c0 + l15];

    f32x4 hO = {0.f, 0.f, 0.f, 0.f};      // fp32 master h (b=16w+quad*4+r, j=c0+l15)

    const int hwrow = (w * 16 + quad * 4) * 1024 + c0 + l15;   // h write (+r*1024)
    const int gxb = w * 16 + quad * 4;
    const int ro = quad * 64 + l15 * 4;   // LDS reduction lane offset

    union HF { u64 q[2]; bf16x8 v; };

    // gx for t=0 (prefetched before each barrier thereafter)
    size_t gbase = (size_t)0 * G3 + c0 + l15;
    ushort4 gv0 = *(const ushort4*)&gx[(gbase) * 64 + gxb];
    ushort4 gv1 = *(const ushort4*)&gx[(gbase + 1024) * 64 + gxb];
    ushort4 gv2 = *(const ushort4*)&gx[(gbase + 2048) * 64 + gxb];

    for (int t = 0; t < 512; ++t) {
        const u16* hc = hbuf + (t & 1) * 65536;
        u16* hn = hbuf + ((t + 1) & 1) * 65536;

        // burst-issue all 32 A-fragments (agent-scope: coherent point)
        HF af[4][8];
#pragma unroll
        for (int mt = 0; mt < 4; ++mt)
#pragma unroll
            for (int s = 0; s < 8; ++s) {
                const u16* p = &hc[(mt * 16 + l15) * 1024 + (ks0 + s) * 32 + quad * 8];
                af[mt][s].q[0] = __hip_atomic_load((const u64*)p, __ATOMIC_RELAXED,
                                                   __HIP_MEMORY_SCOPE_AGENT);
                af[mt][s].q[1] = __hip_atomic_load((const u64*)(p + 4), __ATOMIC_RELAXED,
                                                   __HIP_MEMORY_SCOPE_AGENT);
            }

        f32x4 acc[3][4] = {};
#pragma unroll
        for (int s = 0; s < 8; ++s)
#pragma unroll
            for (int mt = 0; mt < 4; ++mt) {
                const bf16x8 a = af[mt][s].v;
                acc[0][mt] = MFMA16(a, wfr[0][s], acc[0][mt]);
                acc[1][mt] = MFMA16(a, wfr[1][s], acc[1][mt]);
                acc[2][mt] = MFMA16(a, wfr[2][s], acc[2][mt]);
            }

        // cross-wave K-reduction through LDS
#pragma unroll
        for (int g = 0; g < 3; ++g)
#pragma unroll
            for (int mt = 0; mt < 4; ++mt)
                *(f32x4*)&red[g * 4 + mt][w][ro] = acc[g][mt];
        __syncthreads();
        f32x4 a0 = {}, a1 = {}, a2 = {};
#pragma unroll
        for (int wv = 0; wv < 4; ++wv) {
            a0 += *(const f32x4*)&red[0 + w][wv][ro];
            a1 += *(const f32x4*)&red[4 + w][wv][ro];
            a2 += *(const f32x4*)&red[8 + w][wv][ro];
        }

#pragma unroll
        for (int r = 0; r < 4; ++r) {
            const float xr = bf2f(((const u16*)&gv0)[r]);
            const float xz = bf2f(((const u16*)&gv1)[r]);
            const float xn = bf2f(((const u16*)&gv2)[r]);
            const float rg = fast_sigmoid(xr + a0[r] + bh0);
            const float zg = fast_sigmoid(xz + a1[r] + bh1);
            const float ng = fast_tanh(xn + rg * (a2[r] + bh2));
            const float hv = (1.f - zg) * ng + zg * hO[r];
            hO[r] = hv;
            __hip_atomic_store(&hn[hwrow + r * 1024], f2bf(hv), __ATOMIC_RELAXED,
                               __HIP_MEMORY_SCOPE_AGENT);
        }

        // ---- flag barrier (no fences) ----
        __syncthreads();   // drains vmcnt: h stores acked at coherent point
        if (threadIdx.x == 0)
            __hip_atomic_store(&flags[wg * 16], t + 1, __ATOMIC_RELAXED,
                               __HIP_MEMORY_SCOPE_AGENT);
        // prefetch next step's gx while others finish (barrier-independent)
        if (t < 511) {
            gbase = (size_t)(t + 1) * G3 + c0 + l15;
            gv0 = *(const ushort4*)&gx[(gbase) * 64 + gxb];
            gv1 = *(const ushort4*)&gx[(gbase + 1024) * 64 + gxb];
            gv2 = *(const ushort4*)&gx[(gbase + 2048) * 64 + gxb];
        }
        if (w == 0) {
            while (__hip_atomic_load(&flags[lane * 16], __ATOMIC_RELAXED,
                                     __HIP_MEMORY_SCOPE_AGENT) < t + 1) {}
        }
        __syncthreads();
    }

    // fused FC head from registers: hO[r] = h_final(b=16w+quad*4+r, j=c0+l15)
    for (int p = 0; p < 5; ++p) {
        const float wv = wfc[p * 1024 + c0 + l15];
#pragma unroll
        for (int r = 0; r < 4; ++r) {
            float v = hO[r] * wv;
            v += __shfl_xor(v, 1);
            v += __shfl_xor(v, 2);
            v += __shfl_xor(v, 4);
            v += __shfl_xor(v, 8);
            if (l15 == 0)
                atomicAdd(&out[(w * 16 + quad * 4 + r) * 5 + p], v);
        }
    }
}

// --------------------------------------------------------------- launch -----
extern "C" void kernel_launch(void* const* d_in, const int* in_sizes, int n_in,
                              void* d_out, int out_size, void* d_ws, size_t ws_size,
                              hipStream_t stream) {
    const int*   x   = (const int*)d_in[0];
    const float* emb = (const float*)d_in[1];
    const float* wih = (const float*)d_in[2];
    const float* whh = (const float*)d_in[3];
    const float* bih = (const float*)d_in[4];
    const float* bhh = (const float*)d_in[5];
    const float* wfc = (const float*)d_in[6];
    const float* bfc = (const float*)d_in[7];
    float* out = (float*)d_out;

    char* ws = (char*)d_ws;
    u16*   gxw   = (u16*)(ws + OFF_GX);
    u16*   embbf = (u16*)(ws + OFF_EMB);
    u16*   wihbf = (u16*)(ws + OFF_WIH);
    u16*   whhbf = (u16*)(ws + OFF_WHH);
    u16*   hbuf  = (u16*)(ws + OFF_HBUF);
    int*   flags = (int*)(ws + OFF_FLAG);

    prep_kernel<<<8192, 256, 0, stream>>>(x, emb, wih, whh, bfc, embbf, wihbf,
                                          whhbf, hbuf, flags, out);

    gx_gemm<<<dim3(256, 24), 256, 0, stream>>>(embbf, wihbf, bih, gxw);

    scan_kernel<<<64, 256, 0, stream>>>(whhbf, bhh, gxw, hbuf, wfc, out, flags);
}

// Round 5
// 2325.596 us; speedup vs baseline: 3.3516x; 2.1883x over previous
//
#include <hip/hip_runtime.h>
#include <hip/hip_bf16.h>

typedef unsigned short u16;
typedef unsigned long long u64;
typedef __attribute__((ext_vector_type(8))) short bf16x8;   // 8 bf16 in 4 VGPRs
typedef __attribute__((ext_vector_type(4))) float f32x4;    // MFMA acc

#define MFMA16(a, b, c) __builtin_amdgcn_mfma_f32_16x16x32_bf16((a), (b), (c), 0, 0, 0)

static constexpr int Ee = 300, EP = 320, Hh = 1024, G3 = 3072;
static constexpr int Bb = 64, Tt = 512;

// workspace layout (bytes)
static constexpr long OFF_GX   = 0L;                      // [512][3072][64] bf16 = 201326592
static constexpr long OFF_EMB  = 201326592L;              // [32768][320] bf16   = 20971520
static constexpr long OFF_WIH  = 222298112L;              // [3072][320] bf16    = 1966080
static constexpr long OFF_WHH  = 224264192L;              // [3072][1024] bf16   = 6291456
static constexpr long OFF_HBUF = 230555648L;              // 4 grp x 2 x [16][1024] bf16 = 262144
static constexpr long OFF_FLAG = 230817792L;              // counters            = 4096

__device__ __forceinline__ u16 f2bf(float f) {
    union { float f; unsigned u; } v; v.f = f;
    unsigned u = v.u;
    return (u16)((u + 0x7fffu + ((u >> 16) & 1u)) >> 16);   // RNE
}
__device__ __forceinline__ float bf2f(u16 u) {
    union { unsigned u; float f; } v; v.u = ((unsigned)u) << 16;
    return v.f;
}
__device__ __forceinline__ float fast_sigmoid(float x) {
    return 1.f / (1.f + __expf(-x));
}
__device__ __forceinline__ float fast_tanh(float x) {
    float ax = fabsf(x);
    float e = __expf(-2.f * ax);
    float t = (1.f - e) / (1.f + e);
    return copysignf(t, x);
}

// ---------------------------------------------------------------- prep ------
static constexpr long R0 = (long)Bb * Tt * EP;   // emb gather (bf16, padded)
static constexpr long R1 = (long)G3 * EP;        // W_ih -> bf16 padded
static constexpr long R2 = (long)G3 * Hh;        // W_hh -> bf16
static constexpr long R3 = 131072;               // h buffers = 0 (4 grp x 2 x 16K)
static constexpr long R4 = 1024;                 // counters = 0
static constexpr long R5 = 320;                  // out = bias (d_out is poisoned!)

__global__ void prep_kernel(const int* __restrict__ x, const float* __restrict__ emb,
                            const float* __restrict__ wih, const float* __restrict__ whh,
                            const float* __restrict__ bfc,
                            u16* __restrict__ emb_bf, u16* __restrict__ wih_bf,
                            u16* __restrict__ whh_bf, u16* __restrict__ h0,
                            int* __restrict__ cnt, float* __restrict__ out) {
    const long total = R0 + R1 + R2 + R3 + R4 + R5;
    for (long i = (long)blockIdx.x * blockDim.x + threadIdx.x; i < total;
         i += (long)gridDim.x * blockDim.x) {
        if (i < R0) {
            const int m = (int)(i / EP), k = (int)(i % EP);
            const int b = m & 63, t = m >> 6;
            u16 v = 0;
            if (k < Ee) {
                const int xi = x[b * Tt + t];
                v = f2bf(emb[(size_t)xi * Ee + k]);
            }
            emb_bf[i] = v;
        } else if (i < R0 + R1) {
            const long j = i - R0;
            const int k = (int)(j % EP);
            const int n = (int)(j / EP);
            wih_bf[j] = (k < Ee) ? f2bf(wih[(size_t)n * Ee + k]) : (u16)0;
        } else if (i < R0 + R1 + R2) {
            const long j = i - R0 - R1;
            whh_bf[j] = f2bf(whh[j]);
        } else if (i < R0 + R1 + R2 + R3) {
            h0[i - R0 - R1 - R2] = 0;
        } else if (i < R0 + R1 + R2 + R3 + R4) {
            cnt[i - R0 - R1 - R2 - R3] = 0;
        } else {
            const long j = i - R0 - R1 - R2 - R3 - R4;
            out[j] = bfc[j % 5];
        }
    }
}

// ------------------------------------------------------------- gx GEMM ------
// gx[t][n][b] = sum_k emb_bf[m=t*64+b][k] * wih_bf[n][k] + b_ih[n], bf16 out.
__global__ __launch_bounds__(256, 2)
void gx_gemm(const u16* __restrict__ A, const u16* __restrict__ Bm,
             const float* __restrict__ bih, u16* __restrict__ gx) {
    __shared__ __align__(16) u16 lA[128 * 32];
    __shared__ __align__(16) u16 lB[128 * 32];
    const int tid = threadIdx.x;
    const int lane = tid & 63;
    const int wv = tid >> 6;
    const int quad = lane >> 4, l15 = lane & 15;
    const int m0 = blockIdx.x * 128;
    const int n0 = blockIdx.y * 128;
    const int mo = (wv & 1) * 64, no = (wv >> 1) * 64;
    const int srow = tid >> 2;
    const int sseg = tid & 3;

    f32x4 acc[4][4] = {};

    for (int s = 0; s < 10; ++s) {
        const int k0 = s * 32;
        __syncthreads();
#pragma unroll
        for (int p = 0; p < 2; ++p) {
            const u16* ga = A + (size_t)(m0 + p * 64 + srow) * EP + k0 + sseg * 8;
            u16* la = &lA[p * 2048 + wv * 512];
            __builtin_amdgcn_global_load_lds(
                (const __attribute__((address_space(1))) void*)ga,
                (__attribute__((address_space(3))) void*)la, 16, 0, 0);
            const u16* gb = Bm + (size_t)(n0 + p * 64 + srow) * EP + k0 + sseg * 8;
            u16* lb = &lB[p * 2048 + wv * 512];
            __builtin_amdgcn_global_load_lds(
                (const __attribute__((address_space(1))) void*)gb,
                (__attribute__((address_space(3))) void*)lb, 16, 0, 0);
        }
        __syncthreads();

        bf16x8 af[4], bfr[4];
#pragma unroll
        for (int mt = 0; mt < 4; ++mt)
            af[mt] = *(const bf16x8*)&lA[(mo + mt * 16 + l15) * 32 + quad * 8];
#pragma unroll
        for (int nt = 0; nt < 4; ++nt)
            bfr[nt] = *(const bf16x8*)&lB[(no + nt * 16 + l15) * 32 + quad * 8];
#pragma unroll
        for (int mt = 0; mt < 4; ++mt)
#pragma unroll
            for (int nt = 0; nt < 4; ++nt)
                acc[mt][nt] = MFMA16(af[mt], bfr[nt], acc[mt][nt]);
    }

    // C layout: row m = quad*4+r, col n = lane&15
#pragma unroll
    for (int mt = 0; mt < 4; ++mt) {
        const int mg = m0 + mo + mt * 16 + quad * 4;
        const int t = mg >> 6, b0 = mg & 63;
#pragma unroll
        for (int nt = 0; nt < 4; ++nt) {
            const int n = n0 + no + nt * 16 + l15;
            const float bi = bih[n];
            ushort4 vv;
            vv.x = f2bf(acc[mt][nt][0] + bi);
            vv.y = f2bf(acc[mt][nt][1] + bi);
            vv.z = f2bf(acc[mt][nt][2] + bi);
            vv.w = f2bf(acc[mt][nt][3] + bi);
            *(ushort4*)&gx[((size_t)t * G3 + n) * 64 + b0] = vv;
        }
    }
}

// ---------------------------------------------------------------- scan ------
// 128 blocks x 512 thr = 4 INDEPENDENT batch groups (16 rows each) x 32 col
// blocks (32 cols). Waves: kq = K-quarter (0..3), nh = col-half. W frags 24/
// wave (96 VGPR) register-resident. Exchange h[16][1024] bf16 per group (32KB,
// double-buffered): loader waves (nh==0) read it with lane-contiguous u64
// atomic loads -> LDS; all waves ds_read A-frags. Gate waves (w3,w4) do the
// k-reduction, gate math, and ONE packed u64 atomic store. Per-group barrier:
// monotonic atomicAdd counter, loader-wave self-poll.
__global__ __launch_bounds__(512, 2)
void scan_kernel(const u16* __restrict__ whh, const float* __restrict__ bhh,
                 const u16* __restrict__ gx, u16* __restrict__ hbuf,
                 const float* __restrict__ wfc, float* __restrict__ out,
                 int* __restrict__ cnt) {
    __shared__ __align__(16) u16 lh[16 * 1032];          // staged h, padded rows
    __shared__ __align__(16) float red[2][3][4][256];    // [nh][gate][kq][elem]

    const int bid = blockIdx.x;
    const int bg = bid >> 5;          // batch group 0..3 (rows 16bg..+16)
    const int cg = bid & 31;          // col group 0..31 (cols 32cg..+32)
    const int w = threadIdx.x >> 6;   // wave 0..7
    const int lane = threadIdx.x & 63;
    const int kq = w & 3;             // K-quarter
    const int nh = w >> 2;            // col-half for MFMA role
    const int quad = lane >> 4, l15 = lane & 15;
    const int c0 = cg * 32;
    const bool isLoader = (nh == 0);
    const bool isGate = (w == 3) || (w == 4);
    const int gnh = (w == 3) ? 0 : 1; // gate wave's col-half

    // register-resident W: B-frag for col c0+nh*16+l15, gate g, k-chunk kq*8+s
    bf16x8 wf[3][8];
#pragma unroll
    for (int g = 0; g < 3; ++g) {
        const size_t rbase = (size_t)(g * 1024 + c0 + nh * 16 + l15) * 1024;
#pragma unroll
        for (int s = 0; s < 8; ++s)
            wf[g][s] = *(const bf16x8*)&whh[rbase + (kq * 8 + s) * 32 + quad * 8];
    }

    // gate-wave state: per lane handles (b = bg*16 + l15, j = c0+gnh*16+quad*4+jj)
    float bh[3][4];
    u16 gxv[3][4];
    float hO[4] = {0.f, 0.f, 0.f, 0.f};
    if (isGate) {
#pragma unroll
        for (int g = 0; g < 3; ++g)
#pragma unroll
            for (int jj = 0; jj < 4; ++jj) {
                const int jglob = c0 + gnh * 16 + quad * 4 + jj;
                bh[g][jj] = bhh[g * 1024 + jglob];
                gxv[g][jj] = gx[((size_t)0 * G3 + g * 1024 + jglob) * 64 + bg * 16 + l15];
            }
    }

    u16* hb = hbuf + bg * 32768;      // this group's two 16K-elem buffers
    int* mycnt = &cnt[bg * 16];

    for (int t = 0; t < 512; ++t) {
        const u16* hc = hb + (t & 1) * 16384;
        u16* hn = hb + ((t + 1) & 1) * 16384;

        // loaders: pull group's h(t) (32 KB) coalesced -> LDS
        if (isLoader) {
            u64 stg[16];
            const u64* src = (const u64*)hc + kq * 1024 + lane;
#pragma unroll
            for (int r = 0; r < 16; ++r)
                stg[r] = __hip_atomic_load(src + r * 64, __ATOMIC_RELAXED,
                                           __HIP_MEMORY_SCOPE_AGENT);
#pragma unroll
            for (int r = 0; r < 16; ++r) {
                const int row = kq * 4 + (r >> 2);
                const int col = (r & 3) * 256 + lane * 4;
                *(u64*)&lh[row * 1032 + col] = stg[r];
            }
        }
        __syncthreads();

        // MFMA over this wave's K-quarter, 3 gates
        bf16x8 af[8];
#pragma unroll
        for (int s = 0; s < 8; ++s)
            af[s] = *(const bf16x8*)&lh[l15 * 1032 + kq * 256 + s * 32 + quad * 8];
        f32x4 acc[3] = {};
#pragma unroll
        for (int s = 0; s < 8; ++s) {
            acc[0] = MFMA16(af[s], wf[0][s], acc[0]);
            acc[1] = MFMA16(af[s], wf[1][s], acc[1]);
            acc[2] = MFMA16(af[s], wf[2][s], acc[2]);
        }
#pragma unroll
        for (int g = 0; g < 3; ++g)
            *(f32x4*)&red[nh][g][kq][quad * 64 + l15 * 4] = acc[g];
        __syncthreads();

        // gate waves: k-reduce, gate math, packed coalesced h store
        if (isGate) {
            const int eb = (l15 >> 2) * 64 + quad * 16 + (l15 & 3);
            u64 pack = 0;
#pragma unroll
            for (int jj = 0; jj < 4; ++jj) {
                const int e = eb + jj * 4;
                const float s0 = red[gnh][0][0][e] + red[gnh][0][1][e] +
                                 red[gnh][0][2][e] + red[gnh][0][3][e];
                const float s1 = red[gnh][1][0][e] + red[gnh][1][1][e] +
                                 red[gnh][1][2][e] + red[gnh][1][3][e];
                const float s2 = red[gnh][2][0][e] + red[gnh][2][1][e] +
                                 red[gnh][2][2][e] + red[gnh][2][3][e];
                const float rg = fast_sigmoid(bf2f(gxv[0][jj]) + s0 + bh[0][jj]);
                const float zg = fast_sigmoid(bf2f(gxv[1][jj]) + s1 + bh[1][jj]);
                const float ng = fast_tanh(bf2f(gxv[2][jj]) + rg * (s2 + bh[2][jj]));
                const float hv = (1.f - zg) * ng + zg * hO[jj];
                hO[jj] = hv;
                pack |= (u64)f2bf(hv) << (jj * 16);
            }
            __hip_atomic_store((u64*)&hn[l15 * 1024 + c0 + gnh * 16 + quad * 4],
                               pack, __ATOMIC_RELAXED, __HIP_MEMORY_SCOPE_AGENT);
            // prefetch next step's gx (read-only, overlaps barrier)
            if (t < 511) {
#pragma unroll
                for (int g = 0; g < 3; ++g)
#pragma unroll
                    for (int jj = 0; jj < 4; ++jj)
                        gxv[g][jj] = gx[((size_t)(t + 1) * G3 + g * 1024 + c0 +
                                         gnh * 16 + quad * 4 + jj) * 64 + bg * 16 + l15];
            }
        }
        __syncthreads();   // drains gate-wave store (vmcnt) before counter bump
        if (threadIdx.x == 0) atomicAdd(mycnt, 1);
        if (isLoader && t < 511) {
            if (lane == 0) {
                while (__hip_atomic_load(mycnt, __ATOMIC_RELAXED,
                                         __HIP_MEMORY_SCOPE_AGENT) < 32 * (t + 1)) {}
            }
        }
    }

    // FC head from gate-wave registers: hO[jj] = h_T(b = bg*16+l15, j)
    if (isGate) {
#pragma unroll
        for (int p = 0; p < 5; ++p) {
            float v = 0.f;
#pragma unroll
            for (int jj = 0; jj < 4; ++jj)
                v += hO[jj] * wfc[p * 1024 + c0 + gnh * 16 + quad * 4 + jj];
            v += __shfl_xor(v, 16);
            v += __shfl_xor(v, 32);
            if (quad == 0)
                atomicAdd(&out[(bg * 16 + l15) * 5 + p], v);
        }
    }
}

// --------------------------------------------------------------- launch -----
extern "C" void kernel_launch(void* const* d_in, const int* in_sizes, int n_in,
                              void* d_out, int out_size, void* d_ws, size_t ws_size,
                              hipStream_t stream) {
    const int*   x   = (const int*)d_in[0];
    const float* emb = (const float*)d_in[1];
    const float* wih = (const float*)d_in[2];
    const float* whh = (const float*)d_in[3];
    const float* bih = (const float*)d_in[4];
    const float* bhh = (const float*)d_in[5];
    const float* wfc = (const float*)d_in[6];
    const float* bfc = (const float*)d_in[7];
    float* out = (float*)d_out;

    char* ws = (char*)d_ws;
    u16*   gxw   = (u16*)(ws + OFF_GX);
    u16*   embbf = (u16*)(ws + OFF_EMB);
    u16*   wihbf = (u16*)(ws + OFF_WIH);
    u16*   whhbf = (u16*)(ws + OFF_WHH);
    u16*   hbuf  = (u16*)(ws + OFF_HBUF);
    int*   cnt   = (int*)(ws + OFF_FLAG);

    prep_kernel<<<8192, 256, 0, stream>>>(x, emb, wih, whh, bfc, embbf, wihbf,
                                          whhbf, hbuf, cnt, out);

    gx_gemm<<<dim3(256, 24), 256, 0, stream>>>(embbf, wihbf, bih, gxw);

    scan_kernel<<<128, 512, 0, stream>>>(whhbf, bhh, gxw, hbuf, wfc, out, cnt);
}